// Round 1
// baseline (148.183 us; speedup 1.0000x reference)
//
#include <hip/hip_runtime.h>
#include <math.h>

#define BATCH 8192
#define BLK 256

// ---------------- weight LDS offsets (floats) ----------------
// W_fm:0(128) b_fm:128(16) W_c1:144(256) b_c1:400(16) W_p1:416(192) b_p1:608(12)
// W_c2:620(96) b_c2:716(8) W_p2:724(32) b_p2:756(4) W_c3:760(16) b_c3:776(4)
// rot:780(16) ent:796(16)  total 812

template <int IN, int OUT>
__device__ __forceinline__ void layer_tanh(const float* a, float* out,
                                           const float* __restrict__ W,
                                           const float* __restrict__ bias) {
  float acc[OUT];
#pragma unroll
  for (int o = 0; o < OUT; o++) acc[o] = bias[o];
#pragma unroll
  for (int i = 0; i < IN; i++) {
    float ai = a[i];
#pragma unroll
    for (int o = 0; o < OUT; o++) acc[o] = fmaf(ai, W[i * OUT + o], acc[o]);
  }
#pragma unroll
  for (int o = 0; o < OUT; o++) out[o] = tanhf(acc[o]);
}

__global__ __launch_bounds__(BLK) void mlp_kernel(
    const float* __restrict__ in,
    const float* __restrict__ W_fm, const float* __restrict__ b_fm,
    const float* __restrict__ W_c1, const float* __restrict__ b_c1,
    const float* __restrict__ W_p1, const float* __restrict__ b_p1,
    const float* __restrict__ W_c2, const float* __restrict__ b_c2,
    const float* __restrict__ W_p2, const float* __restrict__ b_p2,
    const float* __restrict__ W_c3, const float* __restrict__ b_c3,
    const float* __restrict__ rot, const float* __restrict__ ent,
    float4* __restrict__ xv, float4* __restrict__ qv, float4* __restrict__ kv) {
  __shared__ float w[812];
  const int t = threadIdx.x;
  auto cp = [&](const float* src, int off, int n) {
    for (int i = t; i < n; i += BLK) w[off + i] = src[i];
  };
  cp(W_fm, 0, 128);  cp(b_fm, 128, 16);
  cp(W_c1, 144, 256); cp(b_c1, 400, 16);
  cp(W_p1, 416, 192); cp(b_p1, 608, 12);
  cp(W_c2, 620, 96);  cp(b_c2, 716, 8);
  cp(W_p2, 724, 32);  cp(b_p2, 756, 4);
  cp(W_c3, 760, 16);  cp(b_c3, 776, 4);
  cp(rot, 780, 16);   cp(ent, 796, 16);
  __syncthreads();

  const int r = blockIdx.x * BLK + t;
  const float4* in4 = (const float4*)in;
  float4 i0 = in4[r * 2 + 0];
  float4 i1 = in4[r * 2 + 1];
  float a[16], b[16];
  a[0] = i0.x; a[1] = i0.y; a[2] = i0.z; a[3] = i0.w;
  a[4] = i1.x; a[5] = i1.y; a[6] = i1.z; a[7] = i1.w;

  layer_tanh<8, 16>(a, b, w + 0, w + 128);
  layer_tanh<16, 16>(b, a, w + 144, w + 400);
  layer_tanh<16, 12>(a, b, w + 416, w + 608);
  layer_tanh<12, 8>(b, a, w + 620, w + 716);
  layer_tanh<8, 4>(a, b, w + 724, w + 756);
  layer_tanh<4, 4>(b, a, w + 760, w + 776);
  // final x in a[0..3]
  float q[4], k[4];
#pragma unroll
  for (int d = 0; d < 4; d++) {
    q[d] = a[0] * w[780 + 0 * 4 + d] + a[1] * w[780 + 1 * 4 + d] +
           a[2] * w[780 + 2 * 4 + d] + a[3] * w[780 + 3 * 4 + d];
    k[d] = a[0] * w[796 + 0 * 4 + d] + a[1] * w[796 + 1 * 4 + d] +
           a[2] * w[796 + 2 * 4 + d] + a[3] * w[796 + 3 * 4 + d];
  }
  xv[r] = make_float4(a[0], a[1], a[2], a[3]);
  // fold the 1/sqrt(EMBED)=0.5 softmax scale into q here
  qv[r] = make_float4(q[0] * 0.5f, q[1] * 0.5f, q[2] * 0.5f, q[3] * 0.5f);
  kv[r] = make_float4(k[0], k[1], k[2], k[3]);
}

__device__ __forceinline__ float dot4(float4 a, float4 b) {
  return fmaf(a.x, b.x, fmaf(a.y, b.y, fmaf(a.z, b.z, a.w * b.w)));
}

// Split-K flash attention partial: grid = (BATCH/BLK, NSPLIT); each block
// stages CHUNK keys+values in LDS, each thread owns one query.
template <int CHUNK>
__global__ __launch_bounds__(BLK) void attn_partial(
    const float4* __restrict__ xv, const float4* __restrict__ qv,
    const float4* __restrict__ kv, float* __restrict__ m_arr,
    float* __restrict__ l_arr, float4* __restrict__ o_arr) {
  __shared__ float4 Ks[CHUNK];
  __shared__ float4 Vs[CHUNK];
  const int t = threadIdx.x;
  const int qi = blockIdx.x * BLK + t;
  const int c0 = blockIdx.y * CHUNK;
  for (int i = t; i < CHUNK; i += BLK) {
    Ks[i] = kv[c0 + i];
    Vs[i] = xv[c0 + i];
  }
  __syncthreads();
  const float4 q = qv[qi];

  // pass 1: exact max over this chunk
  float m0 = -3.0e38f, m1 = -3.0e38f;
#pragma unroll 4
  for (int j = 0; j < CHUNK; j += 2) {
    float s0 = dot4(q, Ks[j]);
    float s1 = dot4(q, Ks[j + 1]);
    m0 = fmaxf(m0, s0);
    m1 = fmaxf(m1, s1);
  }
  const float m = fmaxf(m0, m1);

  // pass 2: exp + accumulate
  float l0 = 0.f, l1 = 0.f;
  float4 o0 = make_float4(0.f, 0.f, 0.f, 0.f);
  float4 o1 = make_float4(0.f, 0.f, 0.f, 0.f);
#pragma unroll 4
  for (int j = 0; j < CHUNK; j += 2) {
    float4 ka = Ks[j], kb = Ks[j + 1];
    float4 va = Vs[j], vb = Vs[j + 1];
    float s0 = dot4(q, ka);
    float s1 = dot4(q, kb);
    float p0 = __expf(s0 - m);
    float p1 = __expf(s1 - m);
    l0 += p0;
    l1 += p1;
    o0.x = fmaf(p0, va.x, o0.x); o0.y = fmaf(p0, va.y, o0.y);
    o0.z = fmaf(p0, va.z, o0.z); o0.w = fmaf(p0, va.w, o0.w);
    o1.x = fmaf(p1, vb.x, o1.x); o1.y = fmaf(p1, vb.y, o1.y);
    o1.z = fmaf(p1, vb.z, o1.z); o1.w = fmaf(p1, vb.w, o1.w);
  }
  const int idx = blockIdx.y * BATCH + qi;
  m_arr[idx] = m;
  l_arr[idx] = l0 + l1;
  o_arr[idx] = make_float4(o0.x + o1.x, o0.y + o1.y, o0.z + o1.z, o0.w + o1.w);
}

__global__ __launch_bounds__(BLK) void combine_kernel(
    const float* __restrict__ m_arr, const float* __restrict__ l_arr,
    const float4* __restrict__ o_arr, int nsplit,
    const float* __restrict__ conv_w, const float* __restrict__ conv_b,
    const float* __restrict__ head_w, const float* __restrict__ head_b,
    float* __restrict__ out) {
  const int qi = blockIdx.x * BLK + threadIdx.x;
  float m = -3.0e38f;
  for (int s = 0; s < nsplit; s++) m = fmaxf(m, m_arr[s * BATCH + qi]);
  float l = 0.f;
  float4 o = make_float4(0.f, 0.f, 0.f, 0.f);
  for (int s = 0; s < nsplit; s++) {
    float wgt = __expf(m_arr[s * BATCH + qi] - m);
    l = fmaf(l_arr[s * BATCH + qi], wgt, l);
    float4 os = o_arr[s * BATCH + qi];
    o.x = fmaf(os.x, wgt, o.x); o.y = fmaf(os.y, wgt, o.y);
    o.z = fmaf(os.z, wgt, o.z); o.w = fmaf(os.w, wgt, o.w);
  }
  const float inv = 1.0f / l;
  float z = o.x * inv * conv_w[0] + o.y * inv * conv_w[1] +
            o.z * inv * conv_w[2] + o.w * inv * conv_w[3] + conv_b[0];
  float filtered = 1.0f / (1.0f + __expf(-z));
  float logit = fmaf(filtered, head_w[0], head_b[0]);
  out[qi] = 1.0f / (1.0f + __expf(-logit));
}

extern "C" void kernel_launch(void* const* d_in, const int* in_sizes, int n_in,
                              void* d_out, int out_size, void* d_ws,
                              size_t ws_size, hipStream_t stream) {
  const float* in   = (const float*)d_in[0];
  const float* W_fm = (const float*)d_in[1];
  const float* b_fm = (const float*)d_in[2];
  const float* W_c1 = (const float*)d_in[3];
  const float* b_c1 = (const float*)d_in[4];
  const float* W_p1 = (const float*)d_in[5];
  const float* b_p1 = (const float*)d_in[6];
  const float* W_c2 = (const float*)d_in[7];
  const float* b_c2 = (const float*)d_in[8];
  const float* W_p2 = (const float*)d_in[9];
  const float* b_p2 = (const float*)d_in[10];
  const float* W_c3 = (const float*)d_in[11];
  const float* b_c3 = (const float*)d_in[12];
  const float* rot  = (const float*)d_in[13];
  const float* ent  = (const float*)d_in[14];
  const float* conv_w = (const float*)d_in[15];
  const float* conv_b = (const float*)d_in[16];
  const float* head_w = (const float*)d_in[17];
  const float* head_b = (const float*)d_in[18];
  float* out = (float*)d_out;

  char* ws = (char*)d_ws;
  float4* xv = (float4*)(ws + 0);
  float4* qv = (float4*)(ws + 131072);
  float4* kv = (float4*)(ws + 262144);
  char* part = ws + 393216;

  // choose split count by workspace budget: partials = nsplit*8192*24 bytes
  int nsplit;
  if (ws_size >= (size_t)(393216 + 32 * BATCH * 24))
    nsplit = 32;
  else
    nsplit = 8;

  float* m_arr = (float*)part;
  float* l_arr = (float*)(part + (size_t)nsplit * BATCH * 4);
  float4* o_arr = (float4*)(part + (size_t)nsplit * BATCH * 8);

  mlp_kernel<<<BATCH / BLK, BLK, 0, stream>>>(
      in, W_fm, b_fm, W_c1, b_c1, W_p1, b_p1, W_c2, b_c2, W_p2, b_p2, W_c3,
      b_c3, rot, ent, xv, qv, kv);

  dim3 grid(BATCH / BLK, nsplit);
  if (nsplit == 32) {
    attn_partial<256><<<grid, BLK, 0, stream>>>(xv, qv, kv, m_arr, l_arr, o_arr);
  } else {
    attn_partial<1024><<<grid, BLK, 0, stream>>>(xv, qv, kv, m_arr, l_arr, o_arr);
  }

  combine_kernel<<<BATCH / BLK, BLK, 0, stream>>>(
      m_arr, l_arr, o_arr, nsplit, conv_w, conv_b, head_w, head_b, out);
}

// Round 2
// 130.675 us; speedup vs baseline: 1.1340x; 1.1340x over previous
//
#include <hip/hip_runtime.h>
#include <math.h>

#define BATCH 8192
#define BLK 256
#define NSPLIT 32
#define CHUNK (BATCH / NSPLIT)  // 256 keys per split

// ---------------- weight LDS offsets (floats) ----------------
// W_fm:0(128) b_fm:128(16) W_c1:144(256) b_c1:400(16) W_p1:416(192) b_p1:608(12)
// W_c2:620(96) b_c2:716(8) W_p2:724(32) b_p2:756(4) W_c3:760(16) b_c3:776(4)
// rot:780(16) ent:796(16)  total 812

template <int IN, int OUT>
__device__ __forceinline__ void layer_tanh(const float* a, float* out,
                                           const float* __restrict__ W,
                                           const float* __restrict__ bias) {
  float acc[OUT];
#pragma unroll
  for (int o = 0; o < OUT; o++) acc[o] = bias[o];
#pragma unroll
  for (int i = 0; i < IN; i++) {
    float ai = a[i];
#pragma unroll
    for (int o = 0; o < OUT; o++) acc[o] = fmaf(ai, W[i * OUT + o], acc[o]);
  }
#pragma unroll
  for (int o = 0; o < OUT; o++) out[o] = tanhf(acc[o]);
}

// Produces qv[r] = 0.5 * (x @ rot)  (softmax scale folded)
// and interleaved kvx[2r] = k = x @ ent, kvx[2r+1] = v = x.
__global__ __launch_bounds__(BLK) void mlp_kernel(
    const float* __restrict__ in,
    const float* __restrict__ W_fm, const float* __restrict__ b_fm,
    const float* __restrict__ W_c1, const float* __restrict__ b_c1,
    const float* __restrict__ W_p1, const float* __restrict__ b_p1,
    const float* __restrict__ W_c2, const float* __restrict__ b_c2,
    const float* __restrict__ W_p2, const float* __restrict__ b_p2,
    const float* __restrict__ W_c3, const float* __restrict__ b_c3,
    const float* __restrict__ rot, const float* __restrict__ ent,
    float4* __restrict__ qv, float4* __restrict__ kvx) {
  __shared__ float w[812];
  const int t = threadIdx.x;
  auto cp = [&](const float* src, int off, int n) {
    for (int i = t; i < n; i += BLK) w[off + i] = src[i];
  };
  cp(W_fm, 0, 128);  cp(b_fm, 128, 16);
  cp(W_c1, 144, 256); cp(b_c1, 400, 16);
  cp(W_p1, 416, 192); cp(b_p1, 608, 12);
  cp(W_c2, 620, 96);  cp(b_c2, 716, 8);
  cp(W_p2, 724, 32);  cp(b_p2, 756, 4);
  cp(W_c3, 760, 16);  cp(b_c3, 776, 4);
  cp(rot, 780, 16);   cp(ent, 796, 16);
  __syncthreads();

  const int r = blockIdx.x * BLK + t;
  const float4* in4 = (const float4*)in;
  float4 i0 = in4[r * 2 + 0];
  float4 i1 = in4[r * 2 + 1];
  float a[16], b[16];
  a[0] = i0.x; a[1] = i0.y; a[2] = i0.z; a[3] = i0.w;
  a[4] = i1.x; a[5] = i1.y; a[6] = i1.z; a[7] = i1.w;

  layer_tanh<8, 16>(a, b, w + 0, w + 128);
  layer_tanh<16, 16>(b, a, w + 144, w + 400);
  layer_tanh<16, 12>(a, b, w + 416, w + 608);
  layer_tanh<12, 8>(b, a, w + 620, w + 716);
  layer_tanh<8, 4>(a, b, w + 724, w + 756);
  layer_tanh<4, 4>(b, a, w + 760, w + 776);
  // final x in a[0..3]
  float q[4], k[4];
#pragma unroll
  for (int d = 0; d < 4; d++) {
    q[d] = a[0] * w[780 + 0 * 4 + d] + a[1] * w[780 + 1 * 4 + d] +
           a[2] * w[780 + 2 * 4 + d] + a[3] * w[780 + 3 * 4 + d];
    k[d] = a[0] * w[796 + 0 * 4 + d] + a[1] * w[796 + 1 * 4 + d] +
           a[2] * w[796 + 2 * 4 + d] + a[3] * w[796 + 3 * 4 + d];
  }
  qv[r] = make_float4(q[0] * 0.5f, q[1] * 0.5f, q[2] * 0.5f, q[3] * 0.5f);
  kvx[2 * r + 0] = make_float4(k[0], k[1], k[2], k[3]);
  kvx[2 * r + 1] = make_float4(a[0], a[1], a[2], a[3]);
}

__device__ __forceinline__ float dot4(float4 a, float4 b) {
  return fmaf(a.x, b.x, fmaf(a.y, b.y, fmaf(a.z, b.z, a.w * b.w)));
}

// No-max single-pass split attention. |s| <= ||q||*||k||/2 <= ~32 << 88, so
// exp(s) cannot overflow f32 and the m-rescale cancels in o/l exactly.
// K/V addresses depend only on blockIdx.y and the loop counter -> wave-uniform
// -> compiler emits s_load through the scalar pipe: zero LDS, zero VMEM in
// the hot loop; each v_fma reads at most one SGPR operand (legal encoding).
__global__ __launch_bounds__(BLK) void attn_partial(
    const float4* __restrict__ kvx, const float4* __restrict__ qv,
    float* __restrict__ l_arr, float4* __restrict__ o_arr) {
  const int t = threadIdx.x;
  const int qi = blockIdx.x * BLK + t;
  const int c0 = blockIdx.y * CHUNK;
  const float4 q = qv[qi];

  float l0 = 0.f, l1 = 0.f;
  float4 o0 = make_float4(0.f, 0.f, 0.f, 0.f);
  float4 o1 = make_float4(0.f, 0.f, 0.f, 0.f);
#pragma unroll 4
  for (int j = 0; j < CHUNK; j += 2) {
    const float4 ka = kvx[(c0 + j) * 2 + 0];
    const float4 va = kvx[(c0 + j) * 2 + 1];
    const float4 kb = kvx[(c0 + j) * 2 + 2];
    const float4 vb = kvx[(c0 + j) * 2 + 3];
    float s0 = dot4(q, ka);
    float s1 = dot4(q, kb);
    float p0 = __expf(s0);
    float p1 = __expf(s1);
    l0 += p0;
    l1 += p1;
    o0.x = fmaf(p0, va.x, o0.x); o0.y = fmaf(p0, va.y, o0.y);
    o0.z = fmaf(p0, va.z, o0.z); o0.w = fmaf(p0, va.w, o0.w);
    o1.x = fmaf(p1, vb.x, o1.x); o1.y = fmaf(p1, vb.y, o1.y);
    o1.z = fmaf(p1, vb.z, o1.z); o1.w = fmaf(p1, vb.w, o1.w);
  }
  const int idx = blockIdx.y * BATCH + qi;
  l_arr[idx] = l0 + l1;
  o_arr[idx] = make_float4(o0.x + o1.x, o0.y + o1.y, o0.z + o1.z, o0.w + o1.w);
}

__global__ __launch_bounds__(BLK) void combine_kernel(
    const float* __restrict__ l_arr, const float4* __restrict__ o_arr,
    const float* __restrict__ conv_w, const float* __restrict__ conv_b,
    const float* __restrict__ head_w, const float* __restrict__ head_b,
    float* __restrict__ out) {
  const int qi = blockIdx.x * BLK + threadIdx.x;
  float l = 0.f;
  float4 o = make_float4(0.f, 0.f, 0.f, 0.f);
#pragma unroll
  for (int s = 0; s < NSPLIT; s++) {
    l += l_arr[s * BATCH + qi];
    float4 os = o_arr[s * BATCH + qi];
    o.x += os.x; o.y += os.y; o.z += os.z; o.w += os.w;
  }
  const float inv = 1.0f / l;
  float z = o.x * inv * conv_w[0] + o.y * inv * conv_w[1] +
            o.z * inv * conv_w[2] + o.w * inv * conv_w[3] + conv_b[0];
  float filtered = 1.0f / (1.0f + __expf(-z));
  float logit = fmaf(filtered, head_w[0], head_b[0]);
  out[qi] = 1.0f / (1.0f + __expf(-logit));
}

extern "C" void kernel_launch(void* const* d_in, const int* in_sizes, int n_in,
                              void* d_out, int out_size, void* d_ws,
                              size_t ws_size, hipStream_t stream) {
  const float* in   = (const float*)d_in[0];
  const float* W_fm = (const float*)d_in[1];
  const float* b_fm = (const float*)d_in[2];
  const float* W_c1 = (const float*)d_in[3];
  const float* b_c1 = (const float*)d_in[4];
  const float* W_p1 = (const float*)d_in[5];
  const float* b_p1 = (const float*)d_in[6];
  const float* W_c2 = (const float*)d_in[7];
  const float* b_c2 = (const float*)d_in[8];
  const float* W_p2 = (const float*)d_in[9];
  const float* b_p2 = (const float*)d_in[10];
  const float* W_c3 = (const float*)d_in[11];
  const float* b_c3 = (const float*)d_in[12];
  const float* rot  = (const float*)d_in[13];
  const float* ent  = (const float*)d_in[14];
  const float* conv_w = (const float*)d_in[15];
  const float* conv_b = (const float*)d_in[16];
  const float* head_w = (const float*)d_in[17];
  const float* head_b = (const float*)d_in[18];
  float* out = (float*)d_out;

  char* ws = (char*)d_ws;
  float4* qv  = (float4*)(ws + 0);                 // 128 KB
  float4* kvx = (float4*)(ws + (128 << 10));       // 256 KB (k/v interleaved)
  float*  l_arr = (float*)(ws + (384 << 10));      // NSPLIT*BATCH*4  = 1 MB
  float4* o_arr = (float4*)(ws + (384 << 10) + NSPLIT * BATCH * 4);  // 2 MB

  mlp_kernel<<<BATCH / BLK, BLK, 0, stream>>>(
      in, W_fm, b_fm, W_c1, b_c1, W_p1, b_p1, W_c2, b_c2, W_p2, b_p2, W_c3,
      b_c3, rot, ent, qv, kvx);

  dim3 grid(BATCH / BLK, NSPLIT);
  attn_partial<<<grid, BLK, 0, stream>>>(kvx, qv, l_arr, o_arr);

  combine_kernel<<<BATCH / BLK, BLK, 0, stream>>>(
      l_arr, o_arr, conv_w, conv_b, head_w, head_b, out);
}